// Round 7
// baseline (137.433 us; speedup 1.0000x reference)
//
#include <hip/hip_runtime.h>
#include <math.h>
#include <stdint.h>

#define NJ 14
#define NE 42      // floats per item per tensor
#define TPB 64     // ONE wave per block -> wave-synchronous, zero barriers
#define IPL 2      // items per lane, hand-interleaved for ILP (R6 lesson:
                   // occupancy and chain-length levers are dead; VALUBusy 21%
                   // says 79% dependency stalls -> fill them with a 2nd item)
#define SWEEPS 3   // verified bit-exact vs reference at R6 (absmax 0.0)

__device__ __forceinline__ float frcp(float x) { return __builtin_amdgcn_rcpf(x); }
__device__ __forceinline__ float frsq(float x) { return __builtin_amdgcn_rsqf(x); }
__device__ __forceinline__ float fsqr(float x) { return __builtin_amdgcn_sqrtf(x); }

// Branchless cyclic Jacobi rotation on symmetric A, accumulating V.
template <int p, int q, int r>
__device__ __forceinline__ void jrot(float (&A)[3][3], float (&V)[3][3]) {
    float apq = A[p][q];
    float apq_s = apq + copysignf(1e-30f, apq);
    float tau = (A[q][q] - A[p][p]) * 0.5f * frcp(apq_s);
    float t = copysignf(frcp(fabsf(tau) + fsqr(1.0f + tau * tau)), tau);
    float c = frsq(1.0f + t * t);
    float s = t * c;
    float app = A[p][p], aqq = A[q][q];
    A[p][p] = app - t * apq;
    A[q][q] = aqq + t * apq;
    A[p][q] = 0.0f;
    A[q][p] = 0.0f;
    float arp = A[r][p], arq = A[r][q];
    A[r][p] = c * arp - s * arq;
    A[p][r] = A[r][p];
    A[r][q] = s * arp + c * arq;
    A[q][r] = A[r][q];
#pragma unroll
    for (int k = 0; k < 3; ++k) {
        float vkp = V[k][p], vkq = V[k][q];
        V[k][p] = c * vkp - s * vkq;
        V[k][q] = s * vkp + c * vkq;
    }
}

// Unpack elements e..e+2 (e = 3j, compile-time) from a float2-packed item.
__device__ __forceinline__ void get3(const float2* __restrict__ q2, int e,
                                     float& x, float& y, float& z) {
    float2 a = q2[e / 2];
    float2 b = q2[e / 2 + 1];
    if (e & 1) { x = a.y; y = b.x; z = b.y; }
    else       { x = a.x; y = a.y; z = b.x; }
}

// No LDS, no DMA: 2048 one-wave blocks, VGPR-only -> the ENTIRE grid is
// resident from cycle 0 (8 waves/CU). This removes the residency/dispatch
// and DMA-queue variables that rounds 3-6 could not explain. launch_bounds
// min-waves=1 lifts the compiler's VGPR occupancy heuristic so the 2-item
// interleave fits without scratch spill (round-2: spill = 41 MB WRITE_SIZE).
__global__ __launch_bounds__(TPB, 1) void pampjpe_kernel(
    const float* __restrict__ pred, const float* __restrict__ gt,
    float* __restrict__ out, int n_items) {
    const int lane_base = (blockIdx.x * TPB + threadIdx.x) * IPL;

    const float2* p2[IPL];
    const float2* g2[IPL];
#pragma unroll
    for (int u = 0; u < IPL; ++u) {
        int i = lane_base + u;
        i = i < n_items ? i : n_items - 1;  // clamp (unused: 262144 % 128 == 0)
        p2[u] = (const float2*)pred + i * (NE / 2);
        g2[u] = (const float2*)gt + i * (NE / 2);
    }

    // ---- pass 1: moments, both items interleaved ----
    float Sp[IPL][3], Sg[IPL][3], pp[IPL], M[IPL][3][3];
#pragma unroll
    for (int u = 0; u < IPL; ++u) {
        Sp[u][0] = Sp[u][1] = Sp[u][2] = 0.f;
        Sg[u][0] = Sg[u][1] = Sg[u][2] = 0.f;
        pp[u] = 0.f;
#pragma unroll
        for (int i = 0; i < 3; ++i)
#pragma unroll
            for (int j = 0; j < 3; ++j) M[u][i][j] = 0.f;
    }
#pragma unroll
    for (int j = 0; j < NJ; ++j) {
#pragma unroll
        for (int u = 0; u < IPL; ++u) {
            float px, py, pz, gx, gy, gz;
            get3(p2[u], 3 * j, px, py, pz);
            get3(g2[u], 3 * j, gx, gy, gz);
            Sp[u][0] += px; Sp[u][1] += py; Sp[u][2] += pz;
            Sg[u][0] += gx; Sg[u][1] += gy; Sg[u][2] += gz;
            pp[u] += px * px + py * py + pz * pz;
            M[u][0][0] += px * gx; M[u][0][1] += px * gy; M[u][0][2] += px * gz;
            M[u][1][0] += py * gx; M[u][1][1] += py * gy; M[u][1][2] += py * gz;
            M[u][2][0] += pz * gx; M[u][2][1] += pz * gy; M[u][2][2] += pz * gz;
        }
    }
    // Anti-spill fence (round-2 lesson): input loads die HERE; pass 2 must
    // re-load (cache-hot). Nothing input-sized stays live across Jacobi.
    __asm__ __volatile__("" ::: "memory");

    const float invJ = 1.0f / (float)NJ;
    float mp[IPL][3], mg[IPL][3], sR[IPL][3][3];

#pragma unroll
    for (int u = 0; u < IPL; ++u) {
#pragma unroll
        for (int d = 0; d < 3; ++d) {
            mp[u][d] = Sp[u][d] * invJ;
            mg[u][d] = Sg[u][d] * invJ;
        }
    }

    // Per-item Procrustes; the [u]-unrolled loops put both items' serial
    // chains in one basic block so the scheduler interleaves them.
    float K[IPL][3][3], A[IPL][3][3], V[IPL][3][3], var1[IPL];
#pragma unroll
    for (int u = 0; u < IPL; ++u) {
#pragma unroll
        for (int i = 0; i < 3; ++i)
#pragma unroll
            for (int j = 0; j < 3; ++j)
                K[u][i][j] = M[u][i][j] - (float)NJ * mp[u][i] * mg[u][j];
        var1[u] = pp[u] - (float)NJ * (mp[u][0] * mp[u][0] + mp[u][1] * mp[u][1] +
                                       mp[u][2] * mp[u][2]);
        var1[u] = fmaxf(var1[u], 1e-30f);
#pragma unroll
        for (int i = 0; i < 3; ++i)
#pragma unroll
            for (int j = 0; j < 3; ++j)
                A[u][i][j] = K[u][0][i] * K[u][0][j] + K[u][1][i] * K[u][1][j] +
                             K[u][2][i] * K[u][2][j];
        V[u][0][0] = 1.f; V[u][0][1] = 0.f; V[u][0][2] = 0.f;
        V[u][1][0] = 0.f; V[u][1][1] = 1.f; V[u][1][2] = 0.f;
        V[u][2][0] = 0.f; V[u][2][1] = 0.f; V[u][2][2] = 1.f;
    }
#pragma unroll
    for (int sweep = 0; sweep < SWEEPS; ++sweep) {
#pragma unroll
        for (int u = 0; u < IPL; ++u) {
            jrot<0, 1, 2>(A[u], V[u]);
            jrot<0, 2, 1>(A[u], V[u]);
            jrot<1, 2, 0>(A[u], V[u]);
        }
    }

#pragma unroll
    for (int u = 0; u < IPL; ++u) {
        float lam0 = A[u][0][0], lam1 = A[u][1][1], lam2 = A[u][2][2];
#define SWAPCOL(la, lb, a, b)                                                 \
    {                                                                         \
        float _t;                                                             \
        _t = la; la = lb; lb = _t;                                            \
        _t = V[u][0][a]; V[u][0][a] = V[u][0][b]; V[u][0][b] = _t;            \
        _t = V[u][1][a]; V[u][1][a] = V[u][1][b]; V[u][1][b] = _t;            \
        _t = V[u][2][a]; V[u][2][a] = V[u][2][b]; V[u][2][b] = _t;            \
    }
        if (lam0 < lam1) SWAPCOL(lam0, lam1, 0, 1)
        if (lam0 < lam2) SWAPCOL(lam0, lam2, 0, 2)
        if (lam1 < lam2) SWAPCOL(lam1, lam2, 1, 2)
#undef SWAPCOL

        float v0[3] = {V[u][0][0], V[u][1][0], V[u][2][0]};
        float v1[3] = {V[u][0][1], V[u][1][1], V[u][2][1]};
        float v2[3] = {V[u][0][2], V[u][1][2], V[u][2][2]};

        // det(V) = +1
        float cxx = v0[1] * v1[2] - v0[2] * v1[1];
        float cxy = v0[2] * v1[0] - v0[0] * v1[2];
        float cxz = v0[0] * v1[1] - v0[1] * v1[0];
        float detv = cxx * v2[0] + cxy * v2[1] + cxz * v2[2];
        if (detv < 0.f) { v2[0] = -v2[0]; v2[1] = -v2[1]; v2[2] = -v2[2]; }

        // U via K*v + Gram-Schmidt; u3 = u1 x u2 -> det(U)=+1
        float w0[3], w1[3];
#pragma unroll
        for (int i = 0; i < 3; ++i) {
            w0[i] = K[u][i][0] * v0[0] + K[u][i][1] * v0[1] + K[u][i][2] * v0[2];
            w1[i] = K[u][i][0] * v1[0] + K[u][i][1] * v1[1] + K[u][i][2] * v1[2];
        }
        float inv0 =
            frsq(fmaxf(w0[0] * w0[0] + w0[1] * w0[1] + w0[2] * w0[2], 1e-30f));
        float u1[3] = {w0[0] * inv0, w0[1] * inv0, w0[2] * inv0};
        float d1 = u1[0] * w1[0] + u1[1] * w1[1] + u1[2] * w1[2];
        w1[0] -= d1 * u1[0]; w1[1] -= d1 * u1[1]; w1[2] -= d1 * u1[2];
        float inv1 =
            frsq(fmaxf(w1[0] * w1[0] + w1[1] * w1[1] + w1[2] * w1[2], 1e-30f));
        float u2[3] = {w1[0] * inv1, w1[1] * inv1, w1[2] * inv1};
        float u3[3] = {u1[1] * u2[2] - u1[2] * u2[1],
                       u1[2] * u2[0] - u1[0] * u2[2],
                       u1[0] * u2[1] - u1[1] * u2[0]};

        // R = V U^T; fold scale in afterwards
        float R[3][3];
#pragma unroll
        for (int i = 0; i < 3; ++i) {
            R[i][0] = v0[i] * u1[0] + v1[i] * u2[0] + v2[i] * u3[0];
            R[i][1] = v0[i] * u1[1] + v1[i] * u2[1] + v2[i] * u3[1];
            R[i][2] = v0[i] * u1[2] + v1[i] * u2[2] + v2[i] * u3[2];
        }
        float trRK = 0.f;
#pragma unroll
        for (int i = 0; i < 3; ++i)
#pragma unroll
            for (int j = 0; j < 3; ++j)
                trRK += R[i][j] * K[u][j][i];
        float scale = trRK * frcp(var1[u]);
#pragma unroll
        for (int i = 0; i < 3; ++i)
#pragma unroll
            for (int j = 0; j < 3; ++j)
                sR[u][i][j] = scale * R[i][j];
    }

    // ---- pass 2: loss; inputs re-loaded (cache-hot), both items interleaved ----
    float acc[IPL];
#pragma unroll
    for (int u = 0; u < IPL; ++u) acc[u] = 0.f;
#pragma unroll
    for (int j = 0; j < NJ; ++j) {
#pragma unroll
        for (int u = 0; u < IPL; ++u) {
            float px, py, pz, gx, gy, gz;
            get3(p2[u], 3 * j, px, py, pz);
            get3(g2[u], 3 * j, gx, gy, gz);
            float x0 = px - mp[u][0], x1 = py - mp[u][1], x2 = pz - mp[u][2];
            float y0 = gx - mg[u][0], y1 = gy - mg[u][1], y2 = gz - mg[u][2];
            float e0 = sR[u][0][0] * x0 + sR[u][0][1] * x1 + sR[u][0][2] * x2 - y0;
            float e1 = sR[u][1][0] * x0 + sR[u][1][1] * x1 + sR[u][1][2] * x2 - y1;
            float e2 = sR[u][2][0] * x0 + sR[u][2][1] * x1 + sR[u][2][2] * x2 - y2;
            acc[u] += fsqr(e0 * e0 + e1 * e1 + e2 * e2);
        }
    }
#pragma unroll
    for (int u = 0; u < IPL; ++u) {
        int i = lane_base + u;
        if (i < n_items) out[i] = acc[u] * invJ;
    }
}

extern "C" void kernel_launch(void* const* d_in, const int* in_sizes, int n_in,
                              void* d_out, int out_size, void* d_ws, size_t ws_size,
                              hipStream_t stream) {
    const float* pred = (const float*)d_in[0];
    const float* gt = (const float*)d_in[1];
    float* out = (float*)d_out;
    int n_items = in_sizes[0] / NE;                      // 262144
    int per_blk = TPB * IPL;                             // 128
    int grid = (n_items + per_blk - 1) / per_blk;        // 2048
    pampjpe_kernel<<<grid, TPB, 0, stream>>>(pred, gt, out, n_items);
}

// Round 8
// 109.783 us; speedup vs baseline: 1.2519x; 1.2519x over previous
//
#include <hip/hip_runtime.h>
#include <math.h>
#include <stdint.h>

#define NJ 14
#define NE 42        // floats per item per tensor
#define WPB 4        // waves per block: THE experiment. R1-R7 all used 1-wave
                     // workgroups and occupancy pinned at 3-5 waves/CU no
                     // matter what (dispatch-rate hypothesis). 256-thread wgs
                     // cut workgroup count 4096 -> 1024.
#define TPB (64 * WPB)
#define WAVE_DW (NE * 64)        // 2688 dwords of pred data per wave
#define WAVE_LDS (WAVE_DW + 128) // +pad: tail dma16 writes 64x4 dwords
#define SWEEPS 3     // verified bit-exact vs reference (R6 absmax 0.0)

__device__ __forceinline__ float frcp(float x) { return __builtin_amdgcn_rcpf(x); }
__device__ __forceinline__ float frsq(float x) { return __builtin_amdgcn_rsqf(x); }
__device__ __forceinline__ float fsqr(float x) { return __builtin_amdgcn_sqrtf(x); }

typedef uint32_t u32_as1 __attribute__((address_space(1)));
typedef uint32_t u32_as3 __attribute__((address_space(3)));

__device__ __forceinline__ void dma16(const float* g, const float* l) {
    __builtin_amdgcn_global_load_lds((const u32_as1*)(uintptr_t)g,
                                     (u32_as3*)(uintptr_t)l, 16, 0, 0);
}

// Branchless cyclic Jacobi rotation on symmetric A, accumulating V.
template <int p, int q, int r>
__device__ __forceinline__ void jrot(float A[3][3], float V[3][3]) {
    float apq = A[p][q];
    float apq_s = apq + copysignf(1e-30f, apq);
    float tau = (A[q][q] - A[p][p]) * 0.5f * frcp(apq_s);
    float t = copysignf(frcp(fabsf(tau) + fsqr(1.0f + tau * tau)), tau);
    float c = frsq(1.0f + t * t);
    float s = t * c;
    float app = A[p][p], aqq = A[q][q];
    A[p][p] = app - t * apq;
    A[q][q] = aqq + t * apq;
    A[p][q] = 0.0f;
    A[q][p] = 0.0f;
    float arp = A[r][p], arq = A[r][q];
    A[r][p] = c * arp - s * arq;
    A[p][r] = A[r][p];
    A[r][q] = s * arp + c * arq;
    A[q][r] = A[r][q];
#pragma unroll
    for (int k = 0; k < 3; ++k) {
        float vkp = V[k][p], vkq = V[k][q];
        V[k][p] = c * vkp - s * vkq;
        V[k][q] = s * vkp + c * vkq;
    }
}

// Algorithm per wave is IDENTICAL to rounds 5/6 (measured ~40 us, absmax 0):
//  - pred: wave-private DMA -> LDS quarter, streamed per pass.
//  - gt:   scattered float2 -> VGPR in pass 1 (dies at the fence), re-loaded
//          cache-hot in pass 2. Nothing input-sized lives across Jacobi
//          (round-2 spill lesson). Zero barriers: vmcnt is per-wave, each
//          wave touches only its own LDS quarter.
__global__ __launch_bounds__(TPB) void pampjpe_kernel(
    const float* __restrict__ pred, const float* __restrict__ gt,
    float* __restrict__ out, int n_items) {
    __shared__ float s[WPB * WAVE_LDS];  // 45056 B

    const int tid = threadIdx.x;
    const int w = tid >> 6;         // wave id within block
    const int lane = tid & 63;      // lane id (wave64)
    const int slice = blockIdx.x * WPB + w;      // 64-item slice index
    const int me = slice * 64 + lane;            // item index
    const int blk = slice * WAVE_DW;             // dword base; fits int32
    const int totdw = n_items * NE;
    const int lim4 = totdw - 4;
    float* sw = s + w * WAVE_LDS;   // this wave's LDS quarter

    // ---- pred DMA: 11 x dma16 into the wave's quarter ----
    if (blk + WAVE_DW <= totdw) {
#pragma unroll
        for (int k = 0; k < 10; ++k)
            dma16(pred + blk + k * 256 + lane * 4, sw + k * 256);
        {
            int g = blk + 10 * 256 + lane * 4;
            g = g > lim4 ? lim4 : g;  // lanes >=32 write the pad
            dma16(pred + g, sw + 10 * 256);
        }
    } else {
#pragma unroll
        for (int k = 0; k < 11; ++k) {
            int g = blk + k * 256 + lane * 4;
            g = g > lim4 ? lim4 : g;
            dma16(pred + g, sw + k * 256);
        }
    }

    // ---- gt pass-1 loads, concurrent with the DMAs (item base 8B-aligned) ----
    const int itm = me < n_items ? me : n_items - 1;
    const float2* gp = (const float2*)gt + itm * (NE / 2);
    float2 gv[NE / 2];
#pragma unroll
    for (int k = 0; k < NE / 2; ++k) gv[k] = gp[k];

    __builtin_amdgcn_s_waitcnt(0x0F70);  // vmcnt(0): this wave's loads done
    __builtin_amdgcn_sched_barrier(0);

    const float* sp = sw + lane * NE;  // this lane's pred item (LDS, read-only)

    // ---- pass 1: moments ----
    float Sp0 = 0.f, Sp1 = 0.f, Sp2 = 0.f;
    float Sg0 = 0.f, Sg1 = 0.f, Sg2 = 0.f;
    float pp = 0.f;
    float M[3][3] = {{0.f, 0.f, 0.f}, {0.f, 0.f, 0.f}, {0.f, 0.f, 0.f}};
#pragma unroll
    for (int j = 0; j < NJ; ++j) {
        float px = sp[3 * j + 0], py = sp[3 * j + 1], pz = sp[3 * j + 2];
        float gx, gy, gz;
        {  // compile-time unpack (e known per unrolled j)
            int e = 3 * j;
            gx = (e & 1) ? gv[e / 2].y : gv[e / 2].x;
            gy = ((e + 1) & 1) ? gv[(e + 1) / 2].y : gv[(e + 1) / 2].x;
            gz = ((e + 2) & 1) ? gv[(e + 2) / 2].y : gv[(e + 2) / 2].x;
        }
        Sp0 += px; Sp1 += py; Sp2 += pz;
        Sg0 += gx; Sg1 += gy; Sg2 += gz;
        pp += px * px + py * py + pz * pz;
        M[0][0] += px * gx; M[0][1] += px * gy; M[0][2] += px * gz;
        M[1][0] += py * gx; M[1][1] += py * gy; M[1][2] += py * gz;
        M[2][0] += pz * gx; M[2][1] += pz * gy; M[2][2] += pz * gz;
    }
    // Anti-spill fence: pass-1 loads die here; pass 2 re-loads (round-2 lesson).
    __asm__ __volatile__("" ::: "memory");

    const float invJ = 1.0f / (float)NJ;
    float mp[3] = {Sp0 * invJ, Sp1 * invJ, Sp2 * invJ};
    float mg[3] = {Sg0 * invJ, Sg1 * invJ, Sg2 * invJ};

    float K[3][3];
#pragma unroll
    for (int i = 0; i < 3; ++i)
#pragma unroll
        for (int j = 0; j < 3; ++j)
            K[i][j] = M[i][j] - (float)NJ * mp[i] * mg[j];
    float var1 = pp - (float)NJ * (mp[0] * mp[0] + mp[1] * mp[1] + mp[2] * mp[2]);
    var1 = fmaxf(var1, 1e-30f);

    // ---- A = K^T K, Jacobi ----
    float A[3][3];
#pragma unroll
    for (int i = 0; i < 3; ++i)
#pragma unroll
        for (int j = 0; j < 3; ++j)
            A[i][j] = K[0][i] * K[0][j] + K[1][i] * K[1][j] + K[2][i] * K[2][j];
    float V[3][3] = {{1.f, 0.f, 0.f}, {0.f, 1.f, 0.f}, {0.f, 0.f, 1.f}};
#pragma unroll
    for (int sweep = 0; sweep < SWEEPS; ++sweep) {
        jrot<0, 1, 2>(A, V);
        jrot<0, 2, 1>(A, V);
        jrot<1, 2, 0>(A, V);
    }
    float lam0 = A[0][0], lam1 = A[1][1], lam2 = A[2][2];

#define SWAPCOL(la, lb, a, b)                                     \
    {                                                             \
        float _t;                                                 \
        _t = la; la = lb; lb = _t;                                \
        _t = V[0][a]; V[0][a] = V[0][b]; V[0][b] = _t;            \
        _t = V[1][a]; V[1][a] = V[1][b]; V[1][b] = _t;            \
        _t = V[2][a]; V[2][a] = V[2][b]; V[2][b] = _t;            \
    }
    if (lam0 < lam1) SWAPCOL(lam0, lam1, 0, 1)
    if (lam0 < lam2) SWAPCOL(lam0, lam2, 0, 2)
    if (lam1 < lam2) SWAPCOL(lam1, lam2, 1, 2)
#undef SWAPCOL

    float v0[3] = {V[0][0], V[1][0], V[2][0]};
    float v1[3] = {V[0][1], V[1][1], V[2][1]};
    float v2[3] = {V[0][2], V[1][2], V[2][2]};

    // det(V) = +1
    float cxx = v0[1] * v1[2] - v0[2] * v1[1];
    float cxy = v0[2] * v1[0] - v0[0] * v1[2];
    float cxz = v0[0] * v1[1] - v0[1] * v1[0];
    float detv = cxx * v2[0] + cxy * v2[1] + cxz * v2[2];
    if (detv < 0.f) { v2[0] = -v2[0]; v2[1] = -v2[1]; v2[2] = -v2[2]; }

    // U via K*v + Gram-Schmidt; u3 = u1 x u2 -> det(U)=+1
    float w0[3], w1[3];
#pragma unroll
    for (int i = 0; i < 3; ++i) {
        w0[i] = K[i][0] * v0[0] + K[i][1] * v0[1] + K[i][2] * v0[2];
        w1[i] = K[i][0] * v1[0] + K[i][1] * v1[1] + K[i][2] * v1[2];
    }
    float inv0 = frsq(fmaxf(w0[0] * w0[0] + w0[1] * w0[1] + w0[2] * w0[2], 1e-30f));
    float u1[3] = {w0[0] * inv0, w0[1] * inv0, w0[2] * inv0};
    float d1 = u1[0] * w1[0] + u1[1] * w1[1] + u1[2] * w1[2];
    w1[0] -= d1 * u1[0]; w1[1] -= d1 * u1[1]; w1[2] -= d1 * u1[2];
    float inv1 = frsq(fmaxf(w1[0] * w1[0] + w1[1] * w1[1] + w1[2] * w1[2], 1e-30f));
    float u2[3] = {w1[0] * inv1, w1[1] * inv1, w1[2] * inv1};
    float u3[3] = {u1[1] * u2[2] - u1[2] * u2[1],
                   u1[2] * u2[0] - u1[0] * u2[2],
                   u1[0] * u2[1] - u1[1] * u2[0]};

    // R = V U^T; fold scale in
    float R[3][3];
#pragma unroll
    for (int i = 0; i < 3; ++i) {
        R[i][0] = v0[i] * u1[0] + v1[i] * u2[0] + v2[i] * u3[0];
        R[i][1] = v0[i] * u1[1] + v1[i] * u2[1] + v2[i] * u3[1];
        R[i][2] = v0[i] * u1[2] + v1[i] * u2[2] + v2[i] * u3[2];
    }
    float trRK = 0.f;
#pragma unroll
    for (int i = 0; i < 3; ++i)
#pragma unroll
        for (int j = 0; j < 3; ++j)
            trRK += R[i][j] * K[j][i];
    float scale = trRK * frcp(var1);
    float sR[3][3];
#pragma unroll
    for (int i = 0; i < 3; ++i)
#pragma unroll
        for (int j = 0; j < 3; ++j)
            sR[i][j] = scale * R[i][j];

    // ---- pass 2: gt re-loaded (cache-hot), pred re-streamed from LDS ----
    float2 gw[NE / 2];
#pragma unroll
    for (int k = 0; k < NE / 2; ++k) gw[k] = gp[k];

    float acc = 0.f;
#pragma unroll
    for (int j = 0; j < NJ; ++j) {
        float x0 = sp[3 * j + 0] - mp[0];
        float x1 = sp[3 * j + 1] - mp[1];
        float x2 = sp[3 * j + 2] - mp[2];
        float y0, y1, y2;
        {
            int e = 3 * j;
            y0 = (e & 1) ? gw[e / 2].y : gw[e / 2].x;
            y1 = ((e + 1) & 1) ? gw[(e + 1) / 2].y : gw[(e + 1) / 2].x;
            y2 = ((e + 2) & 1) ? gw[(e + 2) / 2].y : gw[(e + 2) / 2].x;
        }
        y0 -= mg[0]; y1 -= mg[1]; y2 -= mg[2];
        float e0 = sR[0][0] * x0 + sR[0][1] * x1 + sR[0][2] * x2 - y0;
        float e1 = sR[1][0] * x0 + sR[1][1] * x1 + sR[1][2] * x2 - y1;
        float e2 = sR[2][0] * x0 + sR[2][1] * x1 + sR[2][2] * x2 - y2;
        acc += fsqr(e0 * e0 + e1 * e1 + e2 * e2);
    }
    if (me < n_items) out[me] = acc * invJ;
}

extern "C" void kernel_launch(void* const* d_in, const int* in_sizes, int n_in,
                              void* d_out, int out_size, void* d_ws, size_t ws_size,
                              hipStream_t stream) {
    const float* pred = (const float*)d_in[0];
    const float* gt = (const float*)d_in[1];
    float* out = (float*)d_out;
    int n_items = in_sizes[0] / NE;                  // 262144
    int grid = (n_items + TPB - 1) / TPB;            // 1024
    pampjpe_kernel<<<grid, TPB, 0, stream>>>(pred, gt, out, n_items);
}